// Round 1
// baseline (875.930 us; speedup 1.0000x reference)
//
#include <hip/hip_runtime.h>
#include <hip/hip_bf16.h>

#define D_MODEL 96
#define D_INNER 192
#define BATCH 32
#define HH 56
#define WW 56
#define NPIX (BATCH*HH*WW)   // 100352
#define LN_EPS 1e-5f

typedef unsigned short ushort_t;

// round-to-nearest-even f32 -> bf16
static __device__ __forceinline__ unsigned short f2bf(float f) {
    unsigned u = __float_as_uint(f);
    unsigned r = (u + 0x7fffu + ((u >> 16) & 1u)) >> 16;
    return (unsigned short)r;
}
static __device__ __forceinline__ float bf2f(unsigned short s) {
    return __uint_as_float(((unsigned)s) << 16);
}

// ---------------------------------------------------------------------------
// Kernel 1: LayerNorm + in_projection (ONLY the live x1 half: 96 -> 192),
// output x1 as bf16 into workspace.
// Block = 256 threads, 64 pixels per block. Grid = 100352/64 = 1568.
// ---------------------------------------------------------------------------
__global__ __launch_bounds__(256) void k1_ln_proj(
    const float* __restrict__ X, const float* __restrict__ ln_w,
    const float* __restrict__ ln_b, const float* __restrict__ Wi,
    const float* __restrict__ b_in, ushort_t* __restrict__ X1)
{
    __shared__ float sH[64 * 97];   // 64 pixels x 96 normalized channels, pad 97
    const int t = threadIdx.x;

    // ---- LayerNorm: 4 threads per pixel (64 groups) ----
    const int g = t >> 2, tig = t & 3;
    const int pix = blockIdx.x * 64 + g;
    const float* xp = X + (size_t)pix * 96;
    float xv[24];
    float s = 0.f;
    #pragma unroll
    for (int k = 0; k < 24; ++k) { xv[k] = xp[tig + 4 * k]; s += xv[k]; }
    s += __shfl_xor(s, 1, 4);
    s += __shfl_xor(s, 2, 4);
    const float mu = s * (1.f / 96.f);
    float v = 0.f;
    #pragma unroll
    for (int k = 0; k < 24; ++k) { float d = xv[k] - mu; v += d * d; }
    v += __shfl_xor(v, 1, 4);
    v += __shfl_xor(v, 2, 4);
    const float rs = rsqrtf(v * (1.f / 96.f) + LN_EPS);
    #pragma unroll
    for (int k = 0; k < 24; ++k) {
        const int c = tig + 4 * k;
        sH[g * 97 + c] = (xv[k] - mu) * rs * ln_w[c] + ln_b[c];
    }
    __syncthreads();

    // ---- GEMM: 64(px) x 192(oc) x 96(k); thread tile 4 px x 12 oc ----
    const int tm = t >> 4, tn = t & 15;
    float acc[4][12];
    #pragma unroll
    for (int j = 0; j < 12; ++j) {
        const float bj = b_in[tn * 12 + j];
        acc[0][j] = bj; acc[1][j] = bj; acc[2][j] = bj; acc[3][j] = bj;
    }
    const float* sh0 = &sH[(tm * 4 + 0) * 97];
    const float* sh1 = &sH[(tm * 4 + 1) * 97];
    const float* sh2 = &sH[(tm * 4 + 2) * 97];
    const float* sh3 = &sH[(tm * 4 + 3) * 97];
    #pragma unroll 4
    for (int k = 0; k < 96; ++k) {
        const float a0 = sh0[k], a1 = sh1[k], a2 = sh2[k], a3 = sh3[k];
        const float* wr = Wi + k * 384 + tn * 12;   // full row stride 384; x1 half cols
        const float4 w0 = *(const float4*)(wr + 0);
        const float4 w1 = *(const float4*)(wr + 4);
        const float4 w2 = *(const float4*)(wr + 8);
        const float wv[12] = {w0.x, w0.y, w0.z, w0.w, w1.x, w1.y, w1.z, w1.w,
                              w2.x, w2.y, w2.z, w2.w};
        #pragma unroll
        for (int j = 0; j < 12; ++j) {
            acc[0][j] += a0 * wv[j];
            acc[1][j] += a1 * wv[j];
            acc[2][j] += a2 * wv[j];
            acc[3][j] += a3 * wv[j];
        }
    }

    // ---- store x1 as bf16 (3x uint2 per pixel-slice) ----
    #pragma unroll
    for (int i = 0; i < 4; ++i) {
        const int p = blockIdx.x * 64 + tm * 4 + i;
        ushort_t* op = X1 + (size_t)p * 192 + tn * 12;
        uint2 u01, u23, u45;
        u01.x = (unsigned)f2bf(acc[i][0]) | ((unsigned)f2bf(acc[i][1]) << 16);
        u01.y = (unsigned)f2bf(acc[i][2]) | ((unsigned)f2bf(acc[i][3]) << 16);
        u23.x = (unsigned)f2bf(acc[i][4]) | ((unsigned)f2bf(acc[i][5]) << 16);
        u23.y = (unsigned)f2bf(acc[i][6]) | ((unsigned)f2bf(acc[i][7]) << 16);
        u45.x = (unsigned)f2bf(acc[i][8]) | ((unsigned)f2bf(acc[i][9]) << 16);
        u45.y = (unsigned)f2bf(acc[i][10]) | ((unsigned)f2bf(acc[i][11]) << 16);
        *(uint2*)(op + 0) = u01;
        *(uint2*)(op + 4) = u23;
        *(uint2*)(op + 8) = u45;
    }
}

// ---------------------------------------------------------------------------
// Kernel 2: 3x3 conv (192 -> 96, SAME) + bias + SiLU + residual.
// Block = 256 threads, tile = 8x8 output pixels, all 96 oc.
// Halo tile 10x10x192 bf16 staged in LDS (padded to 200 shorts per pixel).
// Thread tile: 4 pixels x 6 oc. Grid = 32 imgs * 49 tiles = 1568.
// ---------------------------------------------------------------------------
__global__ __launch_bounds__(256) void k2_conv_silu_res(
    const ushort_t* __restrict__ X1, const float* __restrict__ Wc,
    const float* __restrict__ conv_b, const float* __restrict__ X,
    float* __restrict__ OUT)
{
    __shared__ ushort_t sX[10 * 10 * 200];   // 40000 B
    const int t = threadIdx.x;
    const int img = blockIdx.x / 49, tile = blockIdx.x % 49;
    const int ty = (tile / 7) * 8, tx = (tile % 7) * 8;

    // ---- stage halo tile (zero-pad at image borders) ----
    for (int idx = t; idx < 2400; idx += 256) {      // 100 px * 24 uint4
        const int pix = idx / 24, q = idx % 24;
        const int prow = pix / 10, pcol = pix % 10;
        const int gr = ty + prow - 1, gc = tx + pcol - 1;
        uint4 val = make_uint4(0u, 0u, 0u, 0u);
        if (gr >= 0 && gr < HH && gc >= 0 && gc < WW) {
            val = *(const uint4*)(X1 + ((size_t)((img * HH + gr) * WW + gc)) * 192 + q * 8);
        }
        *(uint4*)&sX[pix * 200 + q * 8] = val;
    }
    __syncthreads();

    const int pg = t >> 4, og = t & 15;   // 16 pixel-groups x 16 oc-groups
    const int oc0 = og * 6;
    int pbase[4];
    int pr[4], pc[4];
    #pragma unroll
    for (int i = 0; i < 4; ++i) {
        const int p = pg * 4 + i;
        pr[i] = p >> 3; pc[i] = p & 7;
        pbase[i] = (pr[i] * 10 + pc[i]) * 200;
    }

    float acc[4][6];
    #pragma unroll
    for (int j = 0; j < 6; ++j) {
        const float bj = conv_b[oc0 + j];
        acc[0][j] = bj; acc[1][j] = bj; acc[2][j] = bj; acc[3][j] = bj;
    }

    #pragma unroll
    for (int ky = 0; ky < 3; ++ky) {
        #pragma unroll
        for (int kx = 0; kx < 3; ++kx) {
            const float* wp = Wc + ((ky * 3 + kx) * 192) * 96 + oc0;
            const ushort_t* x0 = &sX[pbase[0] + (ky * 10 + kx) * 200];
            const ushort_t* x1p = &sX[pbase[1] + (ky * 10 + kx) * 200];
            const ushort_t* x2 = &sX[pbase[2] + (ky * 10 + kx) * 200];
            const ushort_t* x3 = &sX[pbase[3] + (ky * 10 + kx) * 200];
            #pragma unroll 4
            for (int ic = 0; ic < 192; ++ic) {
                const float2 w01 = *(const float2*)(wp + ic * 96);
                const float2 w23 = *(const float2*)(wp + ic * 96 + 2);
                const float2 w45 = *(const float2*)(wp + ic * 96 + 4);
                const float xs0 = bf2f(x0[ic]);
                const float xs1 = bf2f(x1p[ic]);
                const float xs2 = bf2f(x2[ic]);
                const float xs3 = bf2f(x3[ic]);
                acc[0][0] += xs0 * w01.x; acc[0][1] += xs0 * w01.y;
                acc[0][2] += xs0 * w23.x; acc[0][3] += xs0 * w23.y;
                acc[0][4] += xs0 * w45.x; acc[0][5] += xs0 * w45.y;
                acc[1][0] += xs1 * w01.x; acc[1][1] += xs1 * w01.y;
                acc[1][2] += xs1 * w23.x; acc[1][3] += xs1 * w23.y;
                acc[1][4] += xs1 * w45.x; acc[1][5] += xs1 * w45.y;
                acc[2][0] += xs2 * w01.x; acc[2][1] += xs2 * w01.y;
                acc[2][2] += xs2 * w23.x; acc[2][3] += xs2 * w23.y;
                acc[2][4] += xs2 * w45.x; acc[2][5] += xs2 * w45.y;
                acc[3][0] += xs3 * w01.x; acc[3][1] += xs3 * w01.y;
                acc[3][2] += xs3 * w23.x; acc[3][3] += xs3 * w23.y;
                acc[3][4] += xs3 * w45.x; acc[3][5] += xs3 * w45.y;
            }
        }
    }

    // ---- bias already in acc; SiLU + residual + store ----
    #pragma unroll
    for (int i = 0; i < 4; ++i) {
        const int grow = ty + pr[i], gcol = tx + pc[i];
        const size_t o = ((size_t)((img * HH + grow) * WW + gcol)) * 96 + oc0;
        #pragma unroll
        for (int j = 0; j < 6; ++j) {
            const float y = acc[i][j];
            const float sig = 1.f / (1.f + __expf(-y));
            OUT[o + j] = X[o + j] + y * sig;
        }
    }
}

extern "C" void kernel_launch(void* const* d_in, const int* in_sizes, int n_in,
                              void* d_out, int out_size, void* d_ws, size_t ws_size,
                              hipStream_t stream) {
    (void)in_sizes; (void)n_in; (void)out_size; (void)ws_size;
    const float* X    = (const float*)d_in[0];
    const float* ln_w = (const float*)d_in[1];
    const float* ln_b = (const float*)d_in[2];
    const float* Wi   = (const float*)d_in[3];
    const float* b_in = (const float*)d_in[4];
    const float* Wc   = (const float*)d_in[5];
    const float* cb   = (const float*)d_in[6];
    float* OUT = (float*)d_out;
    ushort_t* X1 = (ushort_t*)d_ws;   // 100352*192 bf16 = 38.5 MB

    k1_ln_proj<<<1568, 256, 0, stream>>>(X, ln_w, ln_b, Wi, b_in, X1);
    k2_conv_silu_res<<<1568, 256, 0, stream>>>(X1, Wc, cb, X, OUT);
}

// Round 2
// 215.136 us; speedup vs baseline: 4.0715x; 4.0715x over previous
//
#include <hip/hip_runtime.h>
#include <hip/hip_bf16.h>

#define D_MODEL 96
#define D_INNER 192
#define BATCH 32
#define HH 56
#define WW 56
#define NPIX (BATCH*HH*WW)   // 100352
#define LN_EPS 1e-5f

typedef unsigned short ushort_t;
typedef __attribute__((ext_vector_type(8))) short short8;   // 8 bf16 (4 VGPRs)
typedef __attribute__((ext_vector_type(4))) float f32x4;

// bf16 conv weights, transposed to [tap][oc][ic] for direct B-fragment loads.
// 9*96*192*2 = 331776 B of module .data — avoids growing d_ws.
__device__ ushort_t g_Wt[9 * 96 * 192];

// round-to-nearest-even f32 -> bf16
static __device__ __forceinline__ unsigned short f2bf(float f) {
    unsigned u = __float_as_uint(f);
    unsigned r = (u + 0x7fffu + ((u >> 16) & 1u)) >> 16;
    return (unsigned short)r;
}

// ---------------------------------------------------------------------------
// Kernel 0: transpose+convert conv weights (3,3,192,96) f32 -> [9][96][192] bf16
// ---------------------------------------------------------------------------
__global__ __launch_bounds__(256) void k0_wt(const float* __restrict__ Wc) {
    const int o = blockIdx.x * 256 + threadIdx.x;
    if (o >= 9 * 96 * 192) return;
    const int tap = o / (96 * 192);
    const int rem = o - tap * 96 * 192;
    const int oc = rem / 192;
    const int ic = rem - oc * 192;
    g_Wt[o] = f2bf(Wc[(tap * 192 + ic) * 96 + oc]);
}

// ---------------------------------------------------------------------------
// Kernel 1: LayerNorm + in_projection (live x1 half only: 96 -> 192),
// x1 stored bf16 pixel-major in workspace. (unchanged from round 1)
// ---------------------------------------------------------------------------
__global__ __launch_bounds__(256) void k1_ln_proj(
    const float* __restrict__ X, const float* __restrict__ ln_w,
    const float* __restrict__ ln_b, const float* __restrict__ Wi,
    const float* __restrict__ b_in, ushort_t* __restrict__ X1)
{
    __shared__ float sH[64 * 97];
    const int t = threadIdx.x;

    const int g = t >> 2, tig = t & 3;
    const int pix = blockIdx.x * 64 + g;
    const float* xp = X + (size_t)pix * 96;
    float xv[24];
    float s = 0.f;
    #pragma unroll
    for (int k = 0; k < 24; ++k) { xv[k] = xp[tig + 4 * k]; s += xv[k]; }
    s += __shfl_xor(s, 1, 4);
    s += __shfl_xor(s, 2, 4);
    const float mu = s * (1.f / 96.f);
    float v = 0.f;
    #pragma unroll
    for (int k = 0; k < 24; ++k) { float d = xv[k] - mu; v += d * d; }
    v += __shfl_xor(v, 1, 4);
    v += __shfl_xor(v, 2, 4);
    const float rs = rsqrtf(v * (1.f / 96.f) + LN_EPS);
    #pragma unroll
    for (int k = 0; k < 24; ++k) {
        const int c = tig + 4 * k;
        sH[g * 97 + c] = (xv[k] - mu) * rs * ln_w[c] + ln_b[c];
    }
    __syncthreads();

    const int tm = t >> 4, tn = t & 15;
    float acc[4][12];
    #pragma unroll
    for (int j = 0; j < 12; ++j) {
        const float bj = b_in[tn * 12 + j];
        acc[0][j] = bj; acc[1][j] = bj; acc[2][j] = bj; acc[3][j] = bj;
    }
    const float* sh0 = &sH[(tm * 4 + 0) * 97];
    const float* sh1 = &sH[(tm * 4 + 1) * 97];
    const float* sh2 = &sH[(tm * 4 + 2) * 97];
    const float* sh3 = &sH[(tm * 4 + 3) * 97];
    #pragma unroll 4
    for (int k = 0; k < 96; ++k) {
        const float a0 = sh0[k], a1 = sh1[k], a2 = sh2[k], a3 = sh3[k];
        const float* wr = Wi + k * 384 + tn * 12;
        const float4 w0 = *(const float4*)(wr + 0);
        const float4 w1 = *(const float4*)(wr + 4);
        const float4 w2 = *(const float4*)(wr + 8);
        const float wv[12] = {w0.x, w0.y, w0.z, w0.w, w1.x, w1.y, w1.z, w1.w,
                              w2.x, w2.y, w2.z, w2.w};
        #pragma unroll
        for (int j = 0; j < 12; ++j) {
            acc[0][j] += a0 * wv[j];
            acc[1][j] += a1 * wv[j];
            acc[2][j] += a2 * wv[j];
            acc[3][j] += a3 * wv[j];
        }
    }

    #pragma unroll
    for (int i = 0; i < 4; ++i) {
        const int p = blockIdx.x * 64 + tm * 4 + i;
        ushort_t* op = X1 + (size_t)p * 192 + tn * 12;
        uint2 u01, u23, u45;
        u01.x = (unsigned)f2bf(acc[i][0]) | ((unsigned)f2bf(acc[i][1]) << 16);
        u01.y = (unsigned)f2bf(acc[i][2]) | ((unsigned)f2bf(acc[i][3]) << 16);
        u23.x = (unsigned)f2bf(acc[i][4]) | ((unsigned)f2bf(acc[i][5]) << 16);
        u23.y = (unsigned)f2bf(acc[i][6]) | ((unsigned)f2bf(acc[i][7]) << 16);
        u45.x = (unsigned)f2bf(acc[i][8]) | ((unsigned)f2bf(acc[i][9]) << 16);
        u45.y = (unsigned)f2bf(acc[i][10]) | ((unsigned)f2bf(acc[i][11]) << 16);
        *(uint2*)(op + 0) = u01;
        *(uint2*)(op + 4) = u23;
        *(uint2*)(op + 8) = u45;
    }
}

// ---------------------------------------------------------------------------
// Kernel 2: 3x3 conv (192 -> 96) as MFMA implicit GEMM + bias + SiLU + residual.
// 1 wave per block, 64 linear pixels per wave (4 m-tiles of 16), N=96 (6 n-tiles).
// A-fragments loaded straight from global X1 (L2/L3-resident, 16B/lane).
// B-fragments from g_Wt[tap][oc][ic] (L2-resident), reused across 4 m-tiles.
// 3136 % 64 == 0 -> a block never crosses an image boundary.
// ---------------------------------------------------------------------------
__global__ __launch_bounds__(64) void k2_conv_mfma(
    const ushort_t* __restrict__ X1, const float* __restrict__ conv_b,
    const float* __restrict__ X, float* __restrict__ OUT)
{
    const int l = threadIdx.x;
    const int lm = l & 15;          // A-row / B-col / D-col lane index
    const int lq = l >> 4;          // k-chunk selector
    const int icq = lq * 8;

    const int P0 = blockIdx.x * 64;
    const int img = P0 / 3136;
    const int ploc0 = P0 - img * 3136;

    int rr[4], cc[4];
    #pragma unroll
    for (int i = 0; i < 4; ++i) {
        const int pl = ploc0 + i * 16 + lm;
        rr[i] = pl / 56;
        cc[i] = pl - rr[i] * 56;
    }
    const size_t imgbase = (size_t)img * 3136 * 192;

    f32x4 acc[4][6];
    const f32x4 zf = {0.f, 0.f, 0.f, 0.f};
    #pragma unroll
    for (int i = 0; i < 4; ++i)
        #pragma unroll
        for (int n = 0; n < 6; ++n) acc[i][n] = zf;

    const short8 zero8 = {0, 0, 0, 0, 0, 0, 0, 0};

    #pragma unroll 1
    for (int ky = 0; ky < 3; ++ky) {
        #pragma unroll 1
        for (int kx = 0; kx < 3; ++kx) {
            const int tap = ky * 3 + kx;
            const ushort_t* abase[4];
            bool av[4];
            #pragma unroll
            for (int i = 0; i < 4; ++i) {
                const int gr = rr[i] + ky - 1, gc = cc[i] + kx - 1;
                av[i] = (gr >= 0) && (gr < HH) && (gc >= 0) && (gc < WW);
                abase[i] = X1 + imgbase + (size_t)(gr * WW + gc) * 192 + icq;
            }
            const ushort_t* bbase = g_Wt + ((size_t)tap * 96 + lm) * 192 + icq;

            #pragma unroll
            for (int kk = 0; kk < 6; ++kk) {
                short8 b[6];
                #pragma unroll
                for (int n = 0; n < 6; ++n)
                    b[n] = *(const short8*)(bbase + n * 16 * 192 + kk * 32);
                short8 a[4];
                #pragma unroll
                for (int i = 0; i < 4; ++i)
                    a[i] = av[i] ? *(const short8*)(abase[i] + kk * 32) : zero8;
                #pragma unroll
                for (int i = 0; i < 4; ++i)
                    #pragma unroll
                    for (int n = 0; n < 6; ++n)
                        acc[i][n] = __builtin_amdgcn_mfma_f32_16x16x32_bf16(
                            a[i], b[n], acc[i][n], 0, 0, 0);
            }
        }
    }

    // D mapping (m89-verified): col = lane&15 -> oc, row = (lane>>4)*4 + reg -> pixel
    #pragma unroll
    for (int n = 0; n < 6; ++n) {
        const int oc = n * 16 + lm;
        const float bv = conv_b[oc];
        #pragma unroll
        for (int i = 0; i < 4; ++i) {
            #pragma unroll
            for (int r4 = 0; r4 < 4; ++r4) {
                const int p = P0 + i * 16 + lq * 4 + r4;
                const size_t o = (size_t)p * 96 + oc;
                const float y = acc[i][n][r4] + bv;
                const float sig = 1.f / (1.f + __expf(-y));
                OUT[o] = X[o] + y * sig;
            }
        }
    }
}

extern "C" void kernel_launch(void* const* d_in, const int* in_sizes, int n_in,
                              void* d_out, int out_size, void* d_ws, size_t ws_size,
                              hipStream_t stream) {
    (void)in_sizes; (void)n_in; (void)out_size; (void)ws_size;
    const float* X    = (const float*)d_in[0];
    const float* ln_w = (const float*)d_in[1];
    const float* ln_b = (const float*)d_in[2];
    const float* Wi   = (const float*)d_in[3];
    const float* b_in = (const float*)d_in[4];
    const float* Wc   = (const float*)d_in[5];
    const float* cb   = (const float*)d_in[6];
    float* OUT = (float*)d_out;
    ushort_t* X1 = (ushort_t*)d_ws;   // 100352*192 bf16 = 38.5 MB

    k0_wt<<<(9 * 96 * 192 + 255) / 256, 256, 0, stream>>>(Wc);
    k1_ln_proj<<<NPIX / 64, 256, 0, stream>>>(X, ln_w, ln_b, Wi, b_in, X1);
    k2_conv_mfma<<<NPIX / 64, 64, 0, stream>>>(X1, cb, X, OUT);
}